// Round 6
// baseline (214.123 us; speedup 1.0000x reference)
//
#include <hip/hip_runtime.h>
#include <hip/hip_fp16.h>
#include <math.h>

#define INV_SQRT2F 0.7071067811865476f

// Pass A: sum(d), sum(d^2) AND store d as fp16 into dcache (33.5 MB) so the
// erf pass never re-reads the 134 MB of inputs.
// asm volatile memory clobber (NOT sched_barrier, which is IntrNoMem and gets
// bypassed by IR sinking - R5 post-mortem) pins 16 independent dwordx4 loads
// before any consumption.
__global__ void __launch_bounds__(256, 4)
pass_sums_store(const float4* __restrict__ pred4, const float4* __restrict__ targ4,
                int n4, ushort4* __restrict__ dcache, float* __restrict__ ws) {
    const int stride = gridDim.x * blockDim.x;
    int i = blockIdx.x * blockDim.x + threadIdx.x;
    float s1 = 0.f, s2 = 0.f;

    for (; i + 7 * stride < n4; i += 8 * stride) {
        float4 p[8], t[8];
#pragma unroll
        for (int u = 0; u < 8; ++u) p[u] = pred4[i + u * stride];
#pragma unroll
        for (int u = 0; u < 8; ++u) t[u] = targ4[i + u * stride];
        asm volatile("" ::: "memory");   // real clobber: loads cannot sink past
#pragma unroll
        for (int u = 0; u < 8; ++u) {
            float d0 = fabsf(p[u].x - t[u].x);
            float d1 = fabsf(p[u].y - t[u].y);
            float d2 = fabsf(p[u].z - t[u].z);
            float d3 = fabsf(p[u].w - t[u].w);
            s1 += (d0 + d1) + (d2 + d3);
            s2 += (d0 * d0 + d1 * d1) + (d2 * d2 + d3 * d3);
            ushort4 h;
            h.x = __half_as_ushort(__float2half(d0));
            h.y = __half_as_ushort(__float2half(d1));
            h.z = __half_as_ushort(__float2half(d2));
            h.w = __half_as_ushort(__float2half(d3));
            dcache[i + u * stride] = h;
        }
    }
    for (; i < n4; i += stride) {          // tail (empty at this problem size)
        float4 p = pred4[i], t = targ4[i];
        float d0 = fabsf(p.x - t.x), d1 = fabsf(p.y - t.y);
        float d2 = fabsf(p.z - t.z), d3 = fabsf(p.w - t.w);
        s1 += (d0 + d1) + (d2 + d3);
        s2 += (d0 * d0 + d1 * d1) + (d2 * d2 + d3 * d3);
        ushort4 h;
        h.x = __half_as_ushort(__float2half(d0));
        h.y = __half_as_ushort(__float2half(d1));
        h.z = __half_as_ushort(__float2half(d2));
        h.w = __half_as_ushort(__float2half(d3));
        dcache[i] = h;
    }

    for (int off = 32; off > 0; off >>= 1) {
        s1 += __shfl_down(s1, off);
        s2 += __shfl_down(s2, off);
    }
    __shared__ float ls1[4], ls2[4];
    int lane = threadIdx.x & 63;
    int wid  = threadIdx.x >> 6;
    if (lane == 0) { ls1[wid] = s1; ls2[wid] = s2; }
    __syncthreads();
    if (threadIdx.x == 0) {
        atomicAdd(&ws[0], (ls1[0] + ls1[1]) + (ls1[2] + ls1[3]));
        atomicAdd(&ws[1], (ls2[0] + ls2[1]) + (ls2[2] + ls2[3]));
    }
}

// Pass B (cached): read fp16 d (33.5 MB, L3-hot) and sum erf(d*k).
__global__ void __launch_bounds__(256, 4)
pass_erf_cached(const ushort4* __restrict__ dcache, int n4, int n,
                float* __restrict__ ws) {
    float sum_d  = ws[0];
    float sum_d2 = ws[1];
    float nf     = (float)n;
    float mean_d = sum_d / nf;
    float var    = (sum_d2 - sum_d * mean_d) / (nf - 1.0f);
    float k      = INV_SQRT2F / var;

    const int stride = gridDim.x * blockDim.x;
    int i = blockIdx.x * blockDim.x + threadIdx.x;
    float s = 0.f;

    for (; i + 7 * stride < n4; i += 8 * stride) {
        ushort4 h[8];
#pragma unroll
        for (int u = 0; u < 8; ++u) h[u] = dcache[i + u * stride];
        asm volatile("" ::: "memory");
#pragma unroll
        for (int u = 0; u < 8; ++u) {
            float d0 = __half2float(__ushort_as_half(h[u].x));
            float d1 = __half2float(__ushort_as_half(h[u].y));
            float d2 = __half2float(__ushort_as_half(h[u].z));
            float d3 = __half2float(__ushort_as_half(h[u].w));
            s += (erff(d0 * k) + erff(d1 * k)) + (erff(d2 * k) + erff(d3 * k));
        }
    }
    for (; i < n4; i += stride) {
        ushort4 h = dcache[i];
        s += (erff(__half2float(__ushort_as_half(h.x)) * k)
            + erff(__half2float(__ushort_as_half(h.y)) * k))
           + (erff(__half2float(__ushort_as_half(h.z)) * k)
            + erff(__half2float(__ushort_as_half(h.w)) * k));
    }

    for (int off = 32; off > 0; off >>= 1)
        s += __shfl_down(s, off);
    __shared__ float ls[4];
    int lane = threadIdx.x & 63;
    int wid  = threadIdx.x >> 6;
    if (lane == 0) ls[wid] = s;
    __syncthreads();
    if (threadIdx.x == 0)
        atomicAdd(&ws[2], (ls[0] + ls[1]) + (ls[2] + ls[3]));
}

// Fallback pass B (re-reads inputs) if ws is too small for the d-cache.
__global__ void __launch_bounds__(256, 4)
pass_erf_full(const float4* __restrict__ pred4, const float4* __restrict__ targ4,
              int n4, int n, float* __restrict__ ws) {
    float sum_d  = ws[0];
    float sum_d2 = ws[1];
    float nf     = (float)n;
    float mean_d = sum_d / nf;
    float var    = (sum_d2 - sum_d * mean_d) / (nf - 1.0f);
    float k      = INV_SQRT2F / var;

    const int stride = gridDim.x * blockDim.x;
    int i = blockIdx.x * blockDim.x + threadIdx.x;
    float s = 0.f;
    for (; i < n4; i += stride) {
        float4 p = pred4[i], t = targ4[i];
        s += (erff(fabsf(p.x - t.x) * k) + erff(fabsf(p.y - t.y) * k))
           + (erff(fabsf(p.z - t.z) * k) + erff(fabsf(p.w - t.w) * k));
    }
    for (int off = 32; off > 0; off >>= 1)
        s += __shfl_down(s, off);
    __shared__ float ls[4];
    int lane = threadIdx.x & 63;
    int wid  = threadIdx.x >> 6;
    if (lane == 0) ls[wid] = s;
    __syncthreads();
    if (threadIdx.x == 0)
        atomicAdd(&ws[2], (ls[0] + ls[1]) + (ls[2] + ls[3]));
}

// Pass A without the store (paired with fallback).
__global__ void __launch_bounds__(256, 4)
pass_sums_plain(const float4* __restrict__ pred4, const float4* __restrict__ targ4,
                int n4, float* __restrict__ ws) {
    const int stride = gridDim.x * blockDim.x;
    int i = blockIdx.x * blockDim.x + threadIdx.x;
    float s1 = 0.f, s2 = 0.f;
    for (; i < n4; i += stride) {
        float4 p = pred4[i], t = targ4[i];
        float d0 = fabsf(p.x - t.x), d1 = fabsf(p.y - t.y);
        float d2 = fabsf(p.z - t.z), d3 = fabsf(p.w - t.w);
        s1 += (d0 + d1) + (d2 + d3);
        s2 += (d0 * d0 + d1 * d1) + (d2 * d2 + d3 * d3);
    }
    for (int off = 32; off > 0; off >>= 1) {
        s1 += __shfl_down(s1, off);
        s2 += __shfl_down(s2, off);
    }
    __shared__ float ls1[4], ls2[4];
    int lane = threadIdx.x & 63;
    int wid  = threadIdx.x >> 6;
    if (lane == 0) { ls1[wid] = s1; ls2[wid] = s2; }
    __syncthreads();
    if (threadIdx.x == 0) {
        atomicAdd(&ws[0], (ls1[0] + ls1[1]) + (ls1[2] + ls1[3]));
        atomicAdd(&ws[1], (ls2[0] + ls2[1]) + (ls2[2] + ls2[3]));
    }
}

__global__ void finalize(const float* __restrict__ ws, float* __restrict__ out, int n) {
    float sum_d   = ws[0];
    float sum_d2  = ws[1];
    float sum_erf = ws[2];
    float nf      = (float)n;
    float mean_d  = sum_d / nf;
    float var     = (sum_d2 - sum_d * mean_d) / (nf - 1.0f);
    float p       = 1.0f - sum_erf / nf;          // p_correct
    float gamma   = -logf(p);
    float coef    = expf(gamma * logf(1.0f - p)); // (1-p)^gamma
    out[0] = coef * mean_d + logf(var + 1.0f);    // LOSS_WEIGHT = 1
}

extern "C" void kernel_launch(void* const* d_in, const int* in_sizes, int n_in,
                              void* d_out, int out_size, void* d_ws, size_t ws_size,
                              hipStream_t stream) {
    const float4* pred4 = (const float4*)d_in[0];
    const float4* targ4 = (const float4*)d_in[1];
    float* out = (float*)d_out;
    float* ws  = (float*)d_ws;
    int n  = in_sizes[0];        // 16777216
    int n4 = n >> 2;

    // ws layout: [0..2] float accumulators; +256 B: fp16 d-cache (n * 2 bytes)
    hipMemsetAsync(d_ws, 0, 3 * sizeof(float), stream);
    ushort4* dcache = (ushort4*)((char*)d_ws + 256);
    bool use_cache = ws_size >= 256 + (size_t)n * 2;

    const int block = 256;
    const int grid  = 2048;      // 2048*256*8 float4 == n4: one-shot load clusters

    if (use_cache) {
        pass_sums_store<<<grid, block, 0, stream>>>(pred4, targ4, n4, dcache, ws);
        pass_erf_cached<<<grid, block, 0, stream>>>(dcache, n4, n, ws);
    } else {
        pass_sums_plain<<<grid, block, 0, stream>>>(pred4, targ4, n4, ws);
        pass_erf_full<<<grid, block, 0, stream>>>(pred4, targ4, n4, n, ws);
    }
    finalize<<<1, 1, 0, stream>>>(ws, out, n);
}